// Round 1
// baseline (471.499 us; speedup 1.0000x reference)
//
#include <hip/hip_runtime.h>
#include <hip/hip_bf16.h>
#include <stdint.h>

#define BB 4
#define CIN 32
#define CO 32
#define NN 256
#define TT 256
#define CMID 224

typedef unsigned short u16;
typedef __attribute__((ext_vector_type(8))) short short8;
typedef __attribute__((ext_vector_type(4))) float f32x4;

__device__ __forceinline__ float bf2f(u16 b){ union {unsigned u; float f;} v; v.u = ((unsigned)b)<<16; return v.f; }
__device__ __forceinline__ u16 f2bf(float f){ union {unsigned u; float f;} v; v.f = f; unsigned r = v.u + 0x7FFF + ((v.u>>16)&1); return (u16)(r>>16); }

__device__ __forceinline__ float ldin(const u16* p){ return bf2f(*p); }
__device__ __forceinline__ float ldin(const float* p){ return *p; }

// ---------------- adaptive adjacency: relu(nv1@nv2), mask zeros to -1e10, row softmax
__global__ __launch_bounds__(256) void k_adp(const float* __restrict__ nv1, const float* __restrict__ nv2,
                                             float* __restrict__ adp){
  int row = blockIdx.x; int j = threadIdx.x;
  float s = 0.f;
  #pragma unroll
  for(int k=0;k<10;k++) s = fmaf(nv1[row*10+k], nv2[k*256+j], s);
  s = s > 0.f ? s : 0.f;
  float val = (s == 0.f) ? -1e10f : s;
  __shared__ float red[256];
  red[j] = val; __syncthreads();
  for(int off=128; off>0; off>>=1){ if(j<off) red[j] = fmaxf(red[j], red[j+off]); __syncthreads(); }
  float m = red[0]; __syncthreads();
  float e = __expf(val - m);
  red[j] = e; __syncthreads();
  for(int off=128; off>0; off>>=1){ if(j<off) red[j] += red[j+off]; __syncthreads(); }
  float sum = red[0];
  adp[row*256+j] = e / sum;
}

// ---------------- adjacency transpose -> bf16: badj[s][w][v] = src_s[v][w]
__global__ __launch_bounds__(256) void k_badj(const float* __restrict__ s0, const float* __restrict__ s1,
                                              const float* __restrict__ adp, u16* __restrict__ badj){
  int s = blockIdx.x >> 8; int w = blockIdx.x & 255; int v = threadIdx.x;
  const float* src = s==0 ? s0 : (s==1 ? s1 : adp);
  badj[(s<<16) + (w<<8) + v] = f2bf(src[v*256 + w]);
}

// ---------------- x [b][c][n][t] f32 -> xT [b][c][t][n] bf16
__global__ __launch_bounds__(256) void k_tin(const float* __restrict__ x, u16* __restrict__ xT){
  int tile = blockIdx.x & 15; int slice = blockIdx.x >> 4;
  int tn0 = (tile & 3) * 64;
  int tt0 = (tile >> 2) * 64;
  const float* src = x + (size_t)slice*65536;
  u16* dst = xT + (size_t)slice*65536;
  __shared__ float lds[64][65];
  int c = threadIdx.x & 63, r0 = threadIdx.x >> 6;
  #pragma unroll
  for(int k=0;k<16;k++){ int r = r0 + 4*k;
    lds[r][c] = src[(tn0 + r)*256 + tt0 + c];
  }
  __syncthreads();
  #pragma unroll
  for(int k=0;k<16;k++){ int r = r0 + 4*k;
    dst[(size_t)(tt0 + r)*256 + tn0 + c] = f2bf(lds[c][r]);
  }
}

// ---------------- gated causal conv in transposed layout: in [b][ci][t][n] -> h bf16 [b][co][t][n]
template<typename TIN>
__global__ __launch_bounds__(256) void k_conv(const TIN* __restrict__ in,
                                              const float* __restrict__ wf, const float* __restrict__ bfv,
                                              const float* __restrict__ wg, const float* __restrict__ bgv,
                                              u16* __restrict__ out, int dil){
  int b = blockIdx.x >> 8; int t = blockIdx.x & 255; int n = threadIdx.x;
  const size_t plane = 65536;
  const TIN* inb = in + (size_t)b*CIN*plane + (size_t)t*256 + n;
  float f[CO], g[CO];
  #pragma unroll
  for(int o=0;o<CO;o++){ f[o]=bfv[o]; g[o]=bgv[o]; }
  for(int i=0;i<CIN;i++){
    float xc = ldin(inb + (size_t)i*plane);
    float xp = (t>=dil) ? ldin(inb + (size_t)i*plane - (size_t)dil*256) : 0.f;
    #pragma unroll
    for(int o=0;o<CO;o++){
      float w0 = wf[(o*CIN+i)*2+0], w1 = wf[(o*CIN+i)*2+1];
      f[o] = fmaf(w1, xc, fmaf(w0, xp, f[o]));
      float v0 = wg[(o*CIN+i)*2+0], v1 = wg[(o*CIN+i)*2+1];
      g[o] = fmaf(v1, xc, fmaf(v0, xp, g[o]));
    }
  }
  u16* ob = out + (size_t)b*CO*plane + (size_t)t*256 + n;
  #pragma unroll
  for(int o=0;o<CO;o++){
    float hv = f[o] / (1.f + __expf(-g[o]));
    ob[(size_t)o*plane] = f2bf(hv);
  }
}

// ---------------- hop GEMM: per b, D[(c,t), w] = sum_v X[b][(c,t)][v] * adj[v][w]
// X bf16 [b][c][t][v-nodes]; Aj bf16 [w][v] (pre-transposed adjacency); Y bf16 [b][c][t][w]
__global__ __launch_bounds__(256) void k_hop(const u16* __restrict__ X, const u16* __restrict__ Aj,
                                             u16* __restrict__ Y){
  __shared__ u16 lds[16384];           // 32 KB: staging [A|B], reused as 128x128 epilogue tile
  u16* lA = lds;
  u16* lB = lds + 8192;
  int tid = threadIdx.x;
  int bid = blockIdx.x;
  int b = bid >> 7, mt = (bid >> 1) & 63, nt = bid & 1;
  const u16* Xb = X + ((size_t)b << 21);
  int m0 = mt << 7, w0 = nt << 7;
  int lane = tid & 63, wave = tid >> 6;
  int wr = (wave >> 1) << 6, wc = (wave & 1) << 6;   // 64x64 quadrant per wave

  f32x4 acc[4][4];
  #pragma unroll
  for(int i=0;i<4;i++)
    #pragma unroll
    for(int j=0;j<4;j++) acc[i][j] = {0.f,0.f,0.f,0.f};

  int srow = tid >> 3;                  // 0..31
  int scb  = (tid & 7) ^ (srow & 7);    // swizzled source col-block
  int ldst = tid * 8;

  for(int kk=0; kk<256; kk+=64){
    __syncthreads();
    #pragma unroll
    for(int q=0;q<4;q++){
      int row = q*32 + srow;
      short8 va = *(const short8*)(Xb + (size_t)(m0+row)*256 + kk + scb*8);
      short8 vb = *(const short8*)(Aj + (size_t)(w0+row)*256 + kk + scb*8);
      *(short8*)&lA[q*2048 + ldst] = va;
      *(short8*)&lB[q*2048 + ldst] = vb;
    }
    __syncthreads();
    #pragma unroll
    for(int ks=0; ks<2; ks++){
      short8 afr[4], bfr[4];
      #pragma unroll
      for(int mf=0; mf<4; mf++){
        int row = wr + mf*16 + (lane & 15);
        int slot = (ks*4 + (lane >> 4)) ^ (row & 7);
        afr[mf] = *(const short8*)&lA[row*64 + slot*8];
      }
      #pragma unroll
      for(int nf=0; nf<4; nf++){
        int row = wc + nf*16 + (lane & 15);
        int slot = (ks*4 + (lane >> 4)) ^ (row & 7);
        bfr[nf] = *(const short8*)&lB[row*64 + slot*8];
      }
      #pragma unroll
      for(int mf=0; mf<4; mf++)
        #pragma unroll
        for(int nf=0; nf<4; nf++)
          acc[mf][nf] = __builtin_amdgcn_mfma_f32_16x16x32_bf16(afr[mf], bfr[nf], acc[mf][nf], 0, 0, 0);
    }
  }

  // epilogue: stage 128x128 tile in LDS (16B-slot XOR swizzle), write coalesced
  __syncthreads();
  #pragma unroll
  for(int mf=0; mf<4; mf++)
    #pragma unroll
    for(int nf=0; nf<4; nf++)
      #pragma unroll
      for(int r=0; r<4; r++){
        int row = wr + mf*16 + (lane>>4)*4 + r;
        int col = wc + nf*16 + (lane&15);
        int byte = col*2;
        int sw = (byte & 15) | ((((byte>>4) ^ (row&15))) << 4);
        *(u16*)((char*)lds + row*256 + sw) = f2bf(acc[mf][nf][r]);
      }
  __syncthreads();
  u16* Yb = Y + ((size_t)b<<21) + (size_t)m0*256 + w0;
  #pragma unroll
  for(int it=0; it<8; it++){
    int row = it*16 + (tid>>4);
    int slot = tid & 15;
    int sw = slot ^ (row & 15);
    short8 v = *(const short8*)((char*)lds + row*256 + sw*16);
    *(short8*)(Yb + (size_t)row*256 + slot*8) = v;
  }
}

// ---------------- mix: out[b][o][t][n] (+)= bias + sum_k sum_c W[o][(wcol0+k)*32+c] * chunk_k[b][c][t][n]
__global__ __launch_bounds__(256) void k_mix(const u16* c0, const u16* c1, const u16* c2, const u16* c3,
                                             const u16* c4, const u16* c5, const u16* c6,
                                             int nch, int wcol0,
                                             const float* __restrict__ wm, const float* __restrict__ bm,
                                             float* __restrict__ out, int init){
  __shared__ float lw[CMID][CO];
  __shared__ float lb[CO];
  int tid = threadIdx.x;
  for(int idx = tid; idx < CO*CMID; idx += 256){
    int o = idx / CMID, cm = idx % CMID;
    lw[cm][o] = wm[idx];
  }
  if(tid < CO) lb[tid] = bm[tid];
  __syncthreads();
  size_t flat = (size_t)blockIdx.x*256 + tid;
  int n = flat & 255; int t = (int)((flat>>8)&255); int b = (int)(flat>>16);
  size_t off = ((size_t)b<<21) + ((size_t)t<<8) + (size_t)n;
  float acc[CO];
  #pragma unroll
  for(int o=0;o<CO;o++) acc[o] = init ? lb[o] : 0.f;

  auto body = [&](const u16* chp, int wcol){
    const u16* ch = chp + off;
    int cmb = wcol*32;
    for(int c=0;c<32;c++){
      float x = bf2f(ch[(size_t)c<<16]);
      const float* w = &lw[cmb + c][0];
      #pragma unroll
      for(int o=0;o<CO;o++) acc[o] = fmaf(w[o], x, acc[o]);
    }
  };
  body(c0, wcol0);
  if(nch>1) body(c1, wcol0+1);
  if(nch>2) body(c2, wcol0+2);
  if(nch>3) body(c3, wcol0+3);
  if(nch>4) body(c4, wcol0+4);
  if(nch>5) body(c5, wcol0+5);
  if(nch>6) body(c6, wcol0+6);

  float* ob = out + off;
  if(init){
    #pragma unroll
    for(int o=0;o<CO;o++) ob[(size_t)o<<16] = acc[o];
  } else {
    #pragma unroll
    for(int o=0;o<CO;o++) ob[(size_t)o<<16] += acc[o];
  }
}

// ---------------- in-place per-slice transpose of d_out: [b][o][t][n] -> [b][o][n][t]
__global__ __launch_bounds__(256) void k_tip(float* __restrict__ d){
  int tp = blockIdx.x % 10; int slice = blockIdx.x / 10;
  int ti, tj;
  if(tp<4){ti=0;tj=tp;} else if(tp<7){ti=1;tj=tp-3;} else if(tp<9){ti=2;tj=tp-5;} else {ti=3;tj=3;}
  float* s = d + (size_t)slice*65536;
  __shared__ float A[64][65];
  __shared__ float Bt[64][65];
  int c = threadIdx.x & 63, r0 = threadIdx.x >> 6;
  int ai = ti*64, aj = tj*64;
  #pragma unroll
  for(int k=0;k<16;k++){ int r = r0+4*k;
    A[r][c]  = s[(size_t)(ai+r)*256 + aj + c];
    Bt[r][c] = s[(size_t)(aj+r)*256 + ai + c];
  }
  __syncthreads();
  #pragma unroll
  for(int k=0;k<16;k++){ int r = r0+4*k;
    s[(size_t)(ai+r)*256 + aj + c] = Bt[c][r];
    s[(size_t)(aj+r)*256 + ai + c] = A[c][r];
  }
}

extern "C" void kernel_launch(void* const* d_in, const int* in_sizes, int n_in,
                              void* d_out, int out_size, void* d_ws, size_t ws_size,
                              hipStream_t stream){
  (void)in_sizes; (void)n_in; (void)out_size;
  const float* x   = (const float*)d_in[0];
  const float* nv1 = (const float*)d_in[1];
  const float* nv2 = (const float*)d_in[2];
  const float* s0  = (const float*)d_in[3];
  const float* s1  = (const float*)d_in[4];
  const float* wf1 = (const float*)d_in[5];  const float* bf1 = (const float*)d_in[6];
  const float* wg1 = (const float*)d_in[7];  const float* bg1 = (const float*)d_in[8];
  const float* wf2 = (const float*)d_in[9];  const float* bf2 = (const float*)d_in[10];
  const float* wg2 = (const float*)d_in[11]; const float* bg2 = (const float*)d_in[12];
  const float* wm1 = (const float*)d_in[13]; const float* bm1 = (const float*)d_in[14];
  const float* wm2 = (const float*)d_in[15]; const float* bm2 = (const float*)d_in[16];
  float* out = (float*)d_out;

  char* ws = (char*)d_ws;
  u16* badj = (u16*)ws;                      // 3 * 256*256*2 = 393216 B
  float* adp = (float*)(ws + 393216);        // 262144 B
  const size_t MB16 = (size_t)16 << 20;
  size_t base = (size_t)1 << 20;
  u16* xT = (u16*)(ws + base);
  u16* h  = (u16*)(ws + base + MB16);
  size_t ybase = base + 2*MB16;
  bool big = ws_size >= ybase + 6*MB16;
  u16* Yb[6];
  int nY = big ? 6 : 2;
  for(int k=0;k<nY;k++) Yb[k] = (u16*)(ws + ybase + (size_t)k*MB16);

  k_adp<<<256,256,0,stream>>>(nv1, nv2, adp);
  k_badj<<<768,256,0,stream>>>(s0, s1, adp, badj);
  k_tin<<<2048,256,0,stream>>>(x, xT);

  const u16* B0 = badj, *B1 = badj+65536, *B2 = badj+131072;
  for(int blk=0; blk<2; blk++){
    if(blk==0) k_conv<u16><<<1024,256,0,stream>>>(xT, wf1,bf1,wg1,bg1, h, 1);
    else       k_conv<float><<<1024,256,0,stream>>>(out, wf2,bf2,wg2,bg2, h, 2);
    const float* wm = blk ? wm2 : wm1;
    const float* bm = blk ? bm2 : bm1;
    if(big){
      k_hop<<<512,256,0,stream>>>(h,     B0, Yb[0]);
      k_hop<<<512,256,0,stream>>>(Yb[0], B0, Yb[1]);
      k_hop<<<512,256,0,stream>>>(h,     B1, Yb[2]);
      k_hop<<<512,256,0,stream>>>(Yb[2], B1, Yb[3]);
      k_hop<<<512,256,0,stream>>>(h,     B2, Yb[4]);
      k_hop<<<512,256,0,stream>>>(Yb[4], B2, Yb[5]);
      k_mix<<<1024,256,0,stream>>>(h,Yb[0],Yb[1],Yb[2],Yb[3],Yb[4],Yb[5], 7, 0, wm, bm, out, 1);
    } else {
      k_mix<<<1024,256,0,stream>>>(h,(const u16*)0,(const u16*)0,(const u16*)0,(const u16*)0,(const u16*)0,(const u16*)0,
                                   1, 0, wm, bm, out, 1);
      const u16* Bs[3] = {B0,B1,B2};
      for(int s=0;s<3;s++){
        k_hop<<<512,256,0,stream>>>(h,     Bs[s], Yb[0]);
        k_hop<<<512,256,0,stream>>>(Yb[0], Bs[s], Yb[1]);
        k_mix<<<1024,256,0,stream>>>(Yb[0],Yb[1],(const u16*)0,(const u16*)0,(const u16*)0,(const u16*)0,(const u16*)0,
                                     2, 1+2*s, wm, bm, out, 0);
      }
    }
  }
  k_tip<<<1280,256,0,stream>>>(out);
}

// Round 2
// 461.986 us; speedup vs baseline: 1.0206x; 1.0206x over previous
//
#include <hip/hip_runtime.h>
#include <hip/hip_bf16.h>
#include <stdint.h>

typedef unsigned short u16;
typedef __attribute__((ext_vector_type(8))) short short8;
typedef __attribute__((ext_vector_type(4))) float f32x4;

__device__ __forceinline__ float bf2f(u16 b){ union {unsigned u; float f;} v; v.u = ((unsigned)b)<<16; return v.f; }
__device__ __forceinline__ u16 f2bf(float f){ union {unsigned u; float f;} v; v.f = f; unsigned r = v.u + 0x7FFF + ((v.u>>16)&1); return (u16)(r>>16); }
__device__ __forceinline__ float ldin(const u16* p){ return bf2f(*p); }
__device__ __forceinline__ float ldin(const float* p){ return *p; }

// ---------------- adaptive adjacency: relu(nv1@nv2), zeros -> -1e10, row softmax
__global__ __launch_bounds__(256) void k_adp(const float* __restrict__ nv1, const float* __restrict__ nv2,
                                             float* __restrict__ adp){
  int row = blockIdx.x; int j = threadIdx.x;
  float s = 0.f;
  #pragma unroll
  for(int k=0;k<10;k++) s = fmaf(nv1[row*10+k], nv2[k*256+j], s);
  s = s > 0.f ? s : 0.f;
  float val = (s == 0.f) ? -1e10f : s;
  __shared__ float red[256];
  red[j] = val; __syncthreads();
  for(int off=128; off>0; off>>=1){ if(j<off) red[j] = fmaxf(red[j], red[j+off]); __syncthreads(); }
  float mx = red[0]; __syncthreads();
  float e = __expf(val - mx);
  red[j] = e; __syncthreads();
  for(int off=128; off>0; off>>=1){ if(j<off) red[j] += red[j+off]; __syncthreads(); }
  float sum = red[0];
  adp[row*256+j] = e / sum;
}

// ---------------- badj[s][w][v] = src_s[v][w]  (bf16, transposed adjacency)
__global__ __launch_bounds__(256) void k_badj(const float* __restrict__ s0, const float* __restrict__ s1,
                                              const float* __restrict__ adp, u16* __restrict__ badj){
  int s = blockIdx.x >> 8; int w = blockIdx.x & 255; int v = threadIdx.x;
  const float* src = s==0 ? s0 : (s==1 ? s1 : adp);
  badj[(s<<16) + (w<<8) + v] = f2bf(src[v*256 + w]);
}

// ---------------- split W (f32) into bf16 hi+lo pairs; [wm1|wm2] each 32*224
__global__ __launch_bounds__(256) void k_wprep(const float* __restrict__ wm1, const float* __restrict__ wm2,
                                               u16* __restrict__ whi, u16* __restrict__ wlo){
  int i = blockIdx.x*256 + threadIdx.x;
  if(i >= 2*7168) return;
  float w = (i < 7168) ? wm1[i] : wm2[i-7168];
  u16 hh = f2bf(w);
  whi[i] = hh;
  wlo[i] = f2bf(w - bf2f(hh));
}

// ---------------- x [b][c][n][t] f32 -> xT [b][t][c][n] bf16
__global__ __launch_bounds__(256) void k_tin(const float* __restrict__ x, u16* __restrict__ xT){
  int tile = blockIdx.x & 15; int slice = blockIdx.x >> 4;   // slice = b*32+c
  int b = slice >> 5, c = slice & 31;
  int tn0 = (tile & 3) * 64;
  int tt0 = (tile >> 2) * 64;
  const float* src = x + (size_t)slice*65536;
  __shared__ float l[64][65];
  int cc = threadIdx.x & 63, r0 = threadIdx.x >> 6;
  #pragma unroll
  for(int k=0;k<16;k++){ int r = r0 + 4*k;
    l[r][cc] = src[(size_t)(tn0 + r)*256 + tt0 + cc];       // row n, col t
  }
  __syncthreads();
  #pragma unroll
  for(int k=0;k<16;k++){ int r = r0 + 4*k;                  // r = t-row
    xT[(((size_t)b*256 + (tt0+r))*32 + c)*256 + tn0 + cc] = f2bf(l[cc][r]);
  }
}

// ---------------- gated causal conv: in [b][t][ci][n] -> h bf16 [b][t][co][n]
template<typename TIN>
__global__ __launch_bounds__(256) void k_conv(const TIN* __restrict__ in,
                                              const float* __restrict__ wf, const float* __restrict__ bfv,
                                              const float* __restrict__ wg, const float* __restrict__ bgv,
                                              u16* __restrict__ out, int dil){
  int bid = blockIdx.x; int b = bid >> 8, t = bid & 255; int n = threadIdx.x;
  const TIN* inb = in + (((size_t)b*256 + t)*32)*256 + n;
  ptrdiff_t dplane = -(ptrdiff_t)dil*32*256;
  float f[32], g[32];
  #pragma unroll
  for(int o=0;o<32;o++){ f[o]=bfv[o]; g[o]=bgv[o]; }
  for(int i=0;i<32;i++){
    float xc = ldin(inb + (size_t)i*256);
    float xp = (t>=dil) ? ldin(inb + (size_t)i*256 + dplane) : 0.f;
    #pragma unroll
    for(int o=0;o<32;o++){
      float w0 = wf[(o*32+i)*2+0], w1 = wf[(o*32+i)*2+1];
      f[o] = fmaf(w1, xc, fmaf(w0, xp, f[o]));
      float v0 = wg[(o*32+i)*2+0], v1 = wg[(o*32+i)*2+1];
      g[o] = fmaf(v1, xc, fmaf(v0, xp, g[o]));
    }
  }
  u16* ob = out + (((size_t)b*256 + t)*32)*256 + n;
  #pragma unroll
  for(int o=0;o<32;o++){
    float hv = f[o] / (1.f + __expf(-g[o]));
    ob[(size_t)o*256] = f2bf(hv);
  }
}

// ---------------- hop GEMM: per b, Y[row, w] = sum_v X[row][v] * adjT[w][v]
// 64-row x 256-col tile per wg; A staged once in swizzled LDS; B-frags direct from L2-hot adjacency.
// split=0: wg loops s_count supports sharing the staged A (src=x0). split=1: grid=512*s_count, support=bid>>9.
__global__ __launch_bounds__(256) void k_hop(const u16* __restrict__ x0, const u16* __restrict__ x1, const u16* __restrict__ x2,
                                             u16* __restrict__ y0, u16* __restrict__ y1, u16* __restrict__ y2,
                                             const u16* __restrict__ badj, int split, int s_base, int s_count){
  __shared__ u16 lds[16384];   // 32 KB: [64 rows][32 x 16B slots], slot XOR-swizzled by row&15
  int tid = threadIdx.x, bid = blockIdx.x;
  int grp = split ? (bid >> 9) : 0;
  int r = split ? (bid & 511) : bid;
  int b = r >> 7, rb = r & 127;
  int m0 = rb << 6;
  const u16* src = grp==0 ? x0 : (grp==1 ? x1 : x2);
  const u16* Xb = src + ((size_t)b << 21);

  // stage A-tile: linear LDS writes, pre-swizzled global source (coalesced at 1KB granularity)
  #pragma unroll
  for(int i=0;i<8;i++){
    int off = i*4096 + tid*16;                 // LDS byte offset
    int row = off >> 9;
    int P = (off >> 4) & 31;                   // physical slot
    int L = (P & 16) | ((P & 15) ^ (row & 15));// logical slot
    short8 v = *(const short8*)((const char*)Xb + (size_t)(m0 + row)*512 + L*16);
    *(short8*)((char*)lds + off) = v;
  }
  __syncthreads();

  int lane = tid & 63, wave = tid >> 6;
  int wr = (wave >> 1) << 5;    // 0 / 32
  int wc = (wave & 1) << 7;     // 0 / 128
  int nsteps = split ? 1 : s_count;

  for(int i=0;i<nsteps;i++){
    int s = s_base + (split ? grp : i);
    const u16* Aj = badj + ((size_t)s << 16);
    u16* dst = split ? (grp==0?y0:(grp==1?y1:y2)) : (i==0?y0:(i==1?y1:y2));
    f32x4 acc[2][8];
    #pragma unroll
    for(int a1=0;a1<2;a1++)
      #pragma unroll
      for(int a2=0;a2<8;a2++) acc[a1][a2] = {0.f,0.f,0.f,0.f};

    #pragma unroll
    for(int ks=0; ks<8; ks++){
      short8 afr[2], bfr[8];
      #pragma unroll
      for(int mf=0; mf<2; mf++){
        int row = wr + mf*16 + (lane & 15);
        int L = ks*4 + (lane >> 4);
        int P = (L & 16) | ((L & 15) ^ (row & 15));
        afr[mf] = *(const short8*)&lds[row*256 + P*8];
      }
      #pragma unroll
      for(int nf=0; nf<8; nf++){
        int w = wc + nf*16 + (lane & 15);
        bfr[nf] = *(const short8*)(Aj + (size_t)w*256 + ks*32 + (lane>>4)*8);
      }
      #pragma unroll
      for(int mf=0;mf<2;mf++)
        #pragma unroll
        for(int nf=0;nf<8;nf++)
          acc[mf][nf] = __builtin_amdgcn_mfma_f32_16x16x32_bf16(afr[mf], bfr[nf], acc[mf][nf], 0,0,0);
    }

    u16* Yb = dst + ((size_t)b<<21) + (size_t)m0*256;
    #pragma unroll
    for(int mf=0;mf<2;mf++)
      #pragma unroll
      for(int nf=0;nf<8;nf++)
        #pragma unroll
        for(int rr=0;rr<4;rr++){
          int row = wr + mf*16 + (lane>>4)*4 + rr;
          int col = wc + nf*16 + (lane&15);
          Yb[(size_t)row*256 + col] = f2bf(acc[mf][nf][rr]);
        }
  }
}

// ---------------- MFMA mix: per (b,t): OUT[32 o][256 n] = sum_{k,c} W[o][k*32+c] * chunk_k[c][n] (+bias)
__global__ __launch_bounds__(256) void k_mix(const u16* c0,const u16* c1,const u16* c2,const u16* c3,
                                             const u16* c4,const u16* c5,const u16* c6,
                                             int nch, int wcol0,
                                             const u16* __restrict__ whi, const u16* __restrict__ wlo,
                                             const float* __restrict__ bm,
                                             float* __restrict__ m, int init){
  __shared__ u16 lds[2][8192];                 // 2 x 16 KB chunk blocks [32 c][256 n]
  int tid = threadIdx.x, bid = blockIdx.x;
  int b = bid >> 8, t = bid & 255;
  size_t cbase = ((size_t)(b*256 + t)) * 8192; // elements
  const u16* chp[7] = {c0,c1,c2,c3,c4,c5,c6};
  int lane = tid & 63, wave = tid >> 6;

  // W fragments (hi+lo) in registers
  short8 wh[7][2], wl[7][2];
  #pragma unroll
  for(int k=0;k<7;k++){
    if(k>=nch) break;
    #pragma unroll
    for(int ot=0;ot<2;ot++){
      int wi = (ot*16 + (lane&15))*224 + (wcol0 + k)*32 + (lane>>4)*8;
      wh[k][ot] = *(const short8*)(whi + wi);
      wl[k][ot] = *(const short8*)(wlo + wi);
    }
  }

  // stage chunk 0
  {
    const char* g = (const char*)(chp[0] + cbase);
    #pragma unroll
    for(int i=0;i<4;i++){
      short8 v = *(const short8*)(g + i*4096 + tid*16);
      *(short8*)((char*)&lds[0][0] + i*4096 + tid*16) = v;
    }
  }
  __syncthreads();

  f32x4 acc[2][4];
  #pragma unroll
  for(int a1=0;a1<2;a1++)
    #pragma unroll
    for(int a2=0;a2<4;a2++) acc[a1][a2] = {0.f,0.f,0.f,0.f};

  int buf = 0;
  #pragma unroll
  for(int k=0;k<7;k++){
    if(k>=nch) break;
    if(k+1 < nch){
      const char* g = (const char*)(chp[k+1] + cbase);
      #pragma unroll
      for(int i=0;i<4;i++){
        short8 v = *(const short8*)(g + i*4096 + tid*16);
        *(short8*)((char*)&lds[buf^1][0] + i*4096 + tid*16) = v;
      }
    }
    #pragma unroll
    for(int nf=0; nf<4; nf++){
      int n = (wave<<6) + (nf<<4) + (lane & 15);
      short8 v;
      #pragma unroll
      for(int j=0;j<8;j++){
        int c = ((lane>>4)<<3) + j;
        v[j] = (short)lds[buf][c*256 + n];
      }
      #pragma unroll
      for(int ot=0;ot<2;ot++){
        acc[ot][nf] = __builtin_amdgcn_mfma_f32_16x16x32_bf16(wh[k][ot], v, acc[ot][nf], 0,0,0);
        acc[ot][nf] = __builtin_amdgcn_mfma_f32_16x16x32_bf16(wl[k][ot], v, acc[ot][nf], 0,0,0);
      }
    }
    __syncthreads();
    buf ^= 1;
  }

  float* mb = m + ((size_t)(b*256 + t)) * 8192;
  #pragma unroll
  for(int ot=0;ot<2;ot++)
    #pragma unroll
    for(int nf=0;nf<4;nf++)
      #pragma unroll
      for(int rr=0;rr<4;rr++){
        int o = ot*16 + (lane>>4)*4 + rr;
        int n = (wave<<6) + (nf<<4) + (lane&15);
        size_t a = (size_t)o*256 + n;
        if(init) mb[a] = acc[ot][nf][rr] + bm[o];
        else     mb[a] += acc[ot][nf][rr];
      }
}

// ---------------- m [b][t][o][n] f32 -> dst [b][o][n][t] f32
__global__ __launch_bounds__(256) void k_tip(const float* __restrict__ m, float* __restrict__ dst){
  int tile = blockIdx.x & 15; int slice = blockIdx.x >> 4;   // slice = b*32+o
  int b = slice >> 5, o = slice & 31;
  int tn0 = (tile & 3) * 64, tt0 = (tile >> 2) * 64;
  __shared__ float l[64][65];
  int cc = threadIdx.x & 63, r0 = threadIdx.x >> 6;
  #pragma unroll
  for(int k=0;k<16;k++){ int r = r0 + 4*k;                   // src row = t
    l[r][cc] = m[(((size_t)b*256 + (tt0+r))*32 + o)*256 + tn0 + cc];
  }
  __syncthreads();
  #pragma unroll
  for(int k=0;k<16;k++){ int r = r0 + 4*k;                   // dst row = n
    dst[(((size_t)b*32 + o)*256 + (tn0+r))*256 + tt0 + cc] = l[cc][r];
  }
}

extern "C" void kernel_launch(void* const* d_in, const int* in_sizes, int n_in,
                              void* d_out, int out_size, void* d_ws, size_t ws_size,
                              hipStream_t stream){
  (void)in_sizes; (void)n_in; (void)out_size;
  const float* x    = (const float*)d_in[0];
  const float* nv1  = (const float*)d_in[1];
  const float* nv2  = (const float*)d_in[2];
  const float* sup0 = (const float*)d_in[3];
  const float* sup1 = (const float*)d_in[4];
  const float* wf1 = (const float*)d_in[5];  const float* bf1v = (const float*)d_in[6];
  const float* wg1 = (const float*)d_in[7];  const float* bg1v = (const float*)d_in[8];
  const float* wf2 = (const float*)d_in[9];  const float* bf2v = (const float*)d_in[10];
  const float* wg2 = (const float*)d_in[11]; const float* bg2v = (const float*)d_in[12];
  const float* wm1 = (const float*)d_in[13]; const float* bm1 = (const float*)d_in[14];
  const float* wm2 = (const float*)d_in[15]; const float* bm2 = (const float*)d_in[16];
  float* out = (float*)d_out;

  char* ws = (char*)d_ws;
  u16* badj = (u16*)ws;                      // 393216 B
  float* adp = (float*)(ws + 393216);        // 262144 B -> 655360
  u16* whi = (u16*)(ws + 655360);            // 28672 B
  u16* wlo = (u16*)(ws + 684032);            // 28672 B -> 712704
  const size_t MB = (size_t)1 << 20;
  const size_t M16 = 16*MB, M32 = 32*MB;
  size_t base = MB;
  size_t need_A = base + M32 + M16 + 6*M16;  // 145 MB: m in ws
  size_t need_B = base + M16 + 6*M16;        // 113 MB: m = d_out, copyback
  int tier = (ws_size >= need_A) ? 0 : ((ws_size >= need_B) ? 1 : 2);

  u16 *xT, *h, *Y[6] = {0,0,0,0,0,0};
  float *m, *tmp = nullptr;
  if(tier==0){
    m  = (float*)(ws + base);
    xT = (u16*)(ws + base);                  // overlaps m; dead before mix1 writes m
    h  = (u16*)(ws + base + M32);
    for(int k=0;k<6;k++) Y[k] = (u16*)(ws + base + M32 + M16 + (size_t)k*M16);
  } else if(tier==1){
    h  = (u16*)(ws + base);
    for(int k=0;k<6;k++) Y[k] = (u16*)(ws + base + M16 + (size_t)k*M16);
    xT = (u16*)(ws + base + M16 + 4*M16);    // Y4 slot; dead before hop1 writes Y4
    m  = out;
    tmp = (float*)(ws + base + M16);         // Y0+Y1 slots, dead at k_tip time
  } else {
    h   = (u16*)(ws + base);
    Y[0] = (u16*)(ws + base + M16);
    Y[1] = (u16*)(ws + base + M32);
    xT  = (u16*)(ws + base + M32);           // Y1 slot; dead before hop2 writes Y1
    m   = out;
    tmp = (float*)(ws + base + M16);
  }

  k_adp<<<256,256,0,stream>>>(nv1, nv2, adp);
  k_badj<<<768,256,0,stream>>>(sup0, sup1, adp, badj);
  k_wprep<<<56,256,0,stream>>>(wm1, wm2, whi, wlo);
  k_tin<<<2048,256,0,stream>>>(x, xT);

  for(int blk=0; blk<2; blk++){
    if(blk==0) k_conv<u16><<<1024,256,0,stream>>>(xT, wf1,bf1v,wg1,bg1v, h, 1);
    else       k_conv<float><<<1024,256,0,stream>>>(m, wf2,bf2v,wg2,bg2v, h, 2);
    const u16* WH = whi + blk*7168;
    const u16* WL = wlo + blk*7168;
    const float* bm = blk ? bm2 : bm1;
    if(tier < 2){
      k_hop<<<512,256,0,stream>>>(h,h,h, Y[0],Y[2],Y[4], badj, 0, 0, 3);
      k_hop<<<1536,256,0,stream>>>(Y[0],Y[2],Y[4], Y[1],Y[3],Y[5], badj, 1, 0, 3);
      k_mix<<<1024,256,0,stream>>>(h,Y[0],Y[1],Y[2],Y[3],Y[4],Y[5], 7, 0, WH, WL, bm, m, 1);
    } else {
      k_mix<<<1024,256,0,stream>>>(h,(const u16*)0,(const u16*)0,(const u16*)0,(const u16*)0,(const u16*)0,(const u16*)0,
                                   1, 0, WH, WL, bm, m, 1);
      for(int s=0;s<3;s++){
        k_hop<<<512,256,0,stream>>>(h,h,h, Y[0],Y[0],Y[0], badj, 0, s, 1);
        k_hop<<<512,256,0,stream>>>(Y[0],Y[0],Y[0], Y[1],Y[1],Y[1], badj, 0, s, 1);
        k_mix<<<1024,256,0,stream>>>(Y[0],Y[1],(const u16*)0,(const u16*)0,(const u16*)0,(const u16*)0,(const u16*)0,
                                     2, 1+2*s, WH, WL, bm, m, 0);
      }
    }
  }
  if(tier==0){
    k_tip<<<2048,256,0,stream>>>(m, out);
  } else {
    k_tip<<<2048,256,0,stream>>>(m, tmp);
    hipMemcpyAsync(out, tmp, (size_t)4*32*256*256*sizeof(float), hipMemcpyDeviceToDevice, stream);
  }
}

// Round 3
// 358.856 us; speedup vs baseline: 1.3139x; 1.2874x over previous
//
#include <hip/hip_runtime.h>
#include <hip/hip_bf16.h>
#include <stdint.h>

typedef unsigned short u16;
typedef __attribute__((ext_vector_type(8))) short short8;
typedef __attribute__((ext_vector_type(4))) short short4v;
typedef __attribute__((ext_vector_type(4))) float f32x4;

__device__ __forceinline__ float bf2f(u16 b){ union {unsigned u; float f;} v; v.u = ((unsigned)b)<<16; return v.f; }
__device__ __forceinline__ u16 f2bf(float f){ union {unsigned u; float f;} v; v.f = f; unsigned r = v.u + 0x7FFF + ((v.u>>16)&1); return (u16)(r>>16); }

// ---------------- adaptive adjacency
__global__ __launch_bounds__(256) void k_adp(const float* __restrict__ nv1, const float* __restrict__ nv2,
                                             float* __restrict__ adp){
  int row = blockIdx.x; int j = threadIdx.x;
  float s = 0.f;
  #pragma unroll
  for(int k=0;k<10;k++) s = fmaf(nv1[row*10+k], nv2[k*256+j], s);
  s = s > 0.f ? s : 0.f;
  float val = (s == 0.f) ? -1e10f : s;
  __shared__ float red[256];
  red[j] = val; __syncthreads();
  for(int off=128; off>0; off>>=1){ if(j<off) red[j] = fmaxf(red[j], red[j+off]); __syncthreads(); }
  float mx = red[0]; __syncthreads();
  float e = __expf(val - mx);
  red[j] = e; __syncthreads();
  for(int off=128; off>0; off>>=1){ if(j<off) red[j] += red[j+off]; __syncthreads(); }
  adp[row*256+j] = e / red[0];
}

// ---------------- badj[s][w][v] = src_s[v][w]
__global__ __launch_bounds__(256) void k_badj(const float* __restrict__ s0, const float* __restrict__ s1,
                                              const float* __restrict__ adp, u16* __restrict__ badj){
  int s = blockIdx.x >> 8; int w = blockIdx.x & 255; int v = threadIdx.x;
  const float* src = s==0 ? s0 : (s==1 ? s1 : adp);
  badj[(s<<16) + (w<<8) + v] = f2bf(src[v*256 + w]);
}

// ---------------- weight prep
__global__ __launch_bounds__(256) void k_wprep(const float* __restrict__ wm1, const float* __restrict__ wm2,
                                               const float* __restrict__ wf1, const float* __restrict__ wg1,
                                               const float* __restrict__ wf2, const float* __restrict__ wg2,
                                               u16* __restrict__ whi, u16* __restrict__ wlo,
                                               u16* __restrict__ wcp){
  int idx = blockIdx.x*256 + threadIdx.x;
  if(idx < 14336){
    float w = (idx < 7168) ? wm1[idx] : wm2[idx-7168];
    u16 hh = f2bf(w);
    whi[idx] = hh;
    wlo[idx] = f2bf(w - bf2f(hh));
  } else {
    int e = idx - 14336;
    int blk = e >> 12; int rem = e & 4095;
    int row = rem >> 6; int kk = rem & 63;
    int tap = kk >> 5; int i = kk & 31; int o = row & 31;
    const float* wsrc = blk ? (row<32 ? wf2 : wg2) : (row<32 ? wf1 : wg1);
    float w = wsrc[(o*32+i)*2 + tap];
    u16 hh = f2bf(w);
    wcp[blk*8192 + 0    + rem] = hh;
    wcp[blk*8192 + 4096 + rem] = f2bf(w - bf2f(hh));
  }
}

// ---------------- x [b][c][n][t] f32 -> xT [b][t][c][n] bf16
__global__ __launch_bounds__(256) void k_tin(const float* __restrict__ x, u16* __restrict__ xT){
  int tile = blockIdx.x & 15; int slice = blockIdx.x >> 4;
  int b = slice >> 5, c = slice & 31;
  int tn0 = (tile & 3) * 64;
  int tt0 = (tile >> 2) * 64;
  const float* src = x + (size_t)slice*65536;
  __shared__ float l[64][65];
  int cc = threadIdx.x & 63, r0 = threadIdx.x >> 6;
  #pragma unroll
  for(int k=0;k<16;k++){ int r = r0 + 4*k;
    l[r][cc] = src[(size_t)(tn0 + r)*256 + tt0 + cc];
  }
  __syncthreads();
  #pragma unroll
  for(int k=0;k<16;k++){ int r = r0 + 4*k;
    xT[(((size_t)b*256 + (tt0+r))*32 + c)*256 + tn0 + cc] = f2bf(l[cc][r]);
  }
}

// ---------------- badj2[s] = badj[s] . badj[s]  (= (A^2)^T stored [w][v])
__global__ __launch_bounds__(256) void k_asq(const u16* __restrict__ badj,
                                             const float* __restrict__ s0, const float* __restrict__ s1,
                                             const float* __restrict__ adp, u16* __restrict__ badj2){
  __shared__ __align__(16) u16 lds[16384];
  int tid = threadIdx.x, bid = blockIdx.x;
  int s = bid >> 2, rt = bid & 3;
  int w0 = rt << 6;
  const u16* T = badj + (s<<16);
  const float* S = s==0 ? s0 : (s==1 ? s1 : adp);
  #pragma unroll
  for(int i=0;i<8;i++){
    int off = i*4096 + tid*16;
    int row = off >> 9;
    int P = (off >> 4) & 31;
    int L = (P & 16) | ((P & 15) ^ (row & 15));
    short8 v = *(const short8*)((const char*)T + (size_t)(w0 + row)*512 + L*16);
    *(short8*)((char*)lds + off) = v;
  }
  __syncthreads();
  int lane = tid & 63, wave = tid >> 6;
  int wr = (wave >> 1) << 5, wc = (wave & 1) << 7;
  f32x4 acc[2][8];
  #pragma unroll
  for(int a=0;a<2;a++)
    #pragma unroll
    for(int q=0;q<8;q++) acc[a][q] = {0.f,0.f,0.f,0.f};
  for(int ks=0; ks<8; ks++){
    short8 afr[2], bfr[8];
    #pragma unroll
    for(int mf=0; mf<2; mf++){
      int row = wr + mf*16 + (lane & 15);
      int L = ks*4 + (lane >> 4);
      int P = (L & 16) | ((L & 15) ^ (row & 15));
      afr[mf] = *(const short8*)&lds[row*256 + P*8];
    }
    #pragma unroll
    for(int nf=0; nf<8; nf++){
      int col = wc + nf*16 + (lane & 15);
      const float* src = S + (size_t)col*256 + ks*32 + (lane>>4)*8;
      #pragma unroll
      for(int jj=0;jj<8;jj++) bfr[nf][jj] = (short)f2bf(src[jj]);
    }
    #pragma unroll
    for(int mf=0;mf<2;mf++)
      #pragma unroll
      for(int nf=0;nf<8;nf++)
        acc[mf][nf] = __builtin_amdgcn_mfma_f32_16x16x32_bf16(afr[mf], bfr[nf], acc[mf][nf], 0,0,0);
  }
  u16* D = badj2 + (s<<16) + (size_t)w0*256;
  #pragma unroll
  for(int mf=0;mf<2;mf++)
    #pragma unroll
    for(int nf=0;nf<8;nf++)
      #pragma unroll
      for(int rr=0;rr<4;rr++){
        int row = wr + mf*16 + (lane>>4)*4 + rr;
        int col = wc + nf*16 + (lane&15);
        D[row*256 + col] = f2bf(acc[mf][nf][rr]);
      }
}

// ---------------- MFMA gated conv (+bias, sigmoid gate)
template<int HILO>
__global__ __launch_bounds__(256) void k_cv(const u16* __restrict__ X0, const u16* __restrict__ X1,
                                            const u16* __restrict__ wcp, int blk, int dil,
                                            const float* __restrict__ bfv, const float* __restrict__ bgv,
                                            u16* __restrict__ outh){
  __shared__ __align__(16) u16 pl[(1+HILO)*2*8192];
  const int NPART = 1+HILO;
  int tid = threadIdx.x, bid = blockIdx.x;
  int b = bid >> 8, t = bid & 255;
  size_t base_cur = ((size_t)(b*256 + t))*8192;
  const u16* Xs[2] = {X0, X1};
  #pragma unroll
  for(int part=0; part<NPART; part++){
    #pragma unroll
    for(int tap=0; tap<2; tap++){
      bool valid = (tap==1) || (t >= dil);
      const u16* src = Xs[part] + base_cur - (tap==0 ? (size_t)dil*8192 : 0);
      char* pb = (char*)pl + (tap*NPART + part)*16384;
      #pragma unroll
      for(int it=0; it<4; it++){
        int off = it*4096 + tid*16;
        int c = off >> 9;
        int byte = off & 511;
        short8 v = {0,0,0,0,0,0,0,0};
        if(valid) v = *(const short8*)(src + (off>>1));
        *(short8*)(pb + c*512 + (byte ^ ((c&24)<<2))) = v;
      }
    }
  }
  int lane = tid & 63, wave = tid >> 6;
  const u16* wb = wcp + blk*8192;
  short8 wfr[4][2][2];
  #pragma unroll
  for(int ot=0;ot<4;ot++)
    #pragma unroll
    for(int ks=0;ks<2;ks++)
      #pragma unroll
      for(int p=0;p<2;p++)
        wfr[ot][ks][p] = *(const short8*)(wb + p*4096 + (ot*16 + (lane&15))*64 + ks*32 + (lane>>4)*8);
  __syncthreads();

  f32x4 acc[4][4];
  #pragma unroll
  for(int a=0;a<4;a++)
    #pragma unroll
    for(int q=0;q<4;q++) acc[a][q] = {0.f,0.f,0.f,0.f};
  int nbase = wave << 6;
  #pragma unroll
  for(int nf=0; nf<4; nf++){
    int n = nbase + nf*16 + (lane & 15);
    #pragma unroll
    for(int ks=0; ks<2; ks++){
      short8 xv[NPART];
      #pragma unroll
      for(int p=0;p<NPART;p++){
        char* pb = (char*)pl + (ks*NPART + p)*16384;
        short8 v;
        #pragma unroll
        for(int jj=0;jj<8;jj++){
          int c = ((lane>>4)<<3) + jj;
          v[jj] = *(const short*)(pb + c*512 + ((n*2) ^ ((c&24)<<2)));
        }
        xv[p] = v;
      }
      #pragma unroll
      for(int ot=0; ot<4; ot++){
        acc[ot][nf] = __builtin_amdgcn_mfma_f32_16x16x32_bf16(wfr[ot][ks][0], xv[0], acc[ot][nf], 0,0,0);
        acc[ot][nf] = __builtin_amdgcn_mfma_f32_16x16x32_bf16(wfr[ot][ks][1], xv[0], acc[ot][nf], 0,0,0);
        if(HILO)
          acc[ot][nf] = __builtin_amdgcn_mfma_f32_16x16x32_bf16(wfr[ot][ks][0], xv[HILO], acc[ot][nf], 0,0,0);
      }
    }
  }
  u16* ob = outh + base_cur;
  #pragma unroll
  for(int ot=0; ot<2; ot++)
    #pragma unroll
    for(int nf=0; nf<4; nf++)
      #pragma unroll
      for(int rr=0; rr<4; rr++){
        int o = ot*16 + (lane>>4)*4 + rr;
        int n = nbase + nf*16 + (lane&15);
        float fv = acc[ot][nf][rr] + bfv[o];
        float gv = acc[ot+2][nf][rr] + bgv[o];
        ob[(size_t)o*256 + n] = f2bf(fv / (1.f + __expf(-gv)));
      }
}

// ---------------- hop GEMMs: stage A-tile of h once, COUNT GEMMs vs [A0,A0^2,A1,A1^2,A2,A2^2]
template<int COUNT>
__global__ __launch_bounds__(256) void k_hop6(const u16* __restrict__ X,
                                              u16* y0, u16* y1, u16* y2, u16* y3, u16* y4, u16* y5,
                                              const u16* __restrict__ badj, const u16* __restrict__ badj2,
                                              int s_base2){
  __shared__ __align__(16) u16 lds[16384];
  int tid = threadIdx.x, bid = blockIdx.x;
  int b = bid >> 7, rb = bid & 127;
  int m0 = rb << 6;
  const u16* Xb = X + ((size_t)b << 21);
  #pragma unroll
  for(int i=0;i<8;i++){
    int off = i*4096 + tid*16;
    int row = off >> 9;
    int P = (off >> 4) & 31;
    int L = (P & 16) | ((P & 15) ^ (row & 15));
    short8 v = *(const short8*)((const char*)Xb + (size_t)(m0 + row)*512 + L*16);
    *(short8*)((char*)lds + off) = v;
  }
  __syncthreads();
  int lane = tid & 63, wave = tid >> 6;
  int wr = (wave >> 1) << 5, wc = (wave & 1) << 7;

  short8 af[2][8];
  #pragma unroll
  for(int mf=0;mf<2;mf++)
    #pragma unroll
    for(int ks=0;ks<8;ks++){
      int row = wr + mf*16 + (lane&15);
      int L = ks*4 + (lane>>4);
      int P = (L&16) | ((L&15)^(row&15));
      af[mf][ks] = *(const short8*)&lds[row*256 + P*8];
    }
  u16* ys[6] = {y0,y1,y2,y3,y4,y5};
  #pragma unroll
  for(int j=0;j<COUNT;j++){
    int vj = s_base2 + j;
    const u16* Aj = ((vj&1)? badj2 : badj) + ((size_t)(vj>>1)<<16);
    f32x4 acc[2][8];
    #pragma unroll
    for(int a=0;a<2;a++)
      #pragma unroll
      for(int q=0;q<8;q++) acc[a][q] = {0.f,0.f,0.f,0.f};
    #pragma unroll
    for(int ks=0;ks<8;ks++){
      short8 bfr[8];
      #pragma unroll
      for(int nf=0;nf<8;nf++){
        int w = wc + nf*16 + (lane&15);
        bfr[nf] = *(const short8*)(Aj + (size_t)w*256 + ks*32 + (lane>>4)*8);
      }
      #pragma unroll
      for(int mf=0;mf<2;mf++)
        #pragma unroll
        for(int nf=0;nf<8;nf++)
          acc[mf][nf] = __builtin_amdgcn_mfma_f32_16x16x32_bf16(af[mf][ks], bfr[nf], acc[mf][nf], 0,0,0);
    }
    u16* Yb = ys[j] + ((size_t)b<<21) + (size_t)m0*256;
    #pragma unroll
    for(int mf=0;mf<2;mf++)
      #pragma unroll
      for(int nf=0;nf<8;nf++)
        #pragma unroll
        for(int rr=0;rr<4;rr++){
          int row = wr + mf*16 + (lane>>4)*4 + rr;
          int col = wc + nf*16 + (lane&15);
          Yb[(size_t)row*256 + col] = f2bf(acc[mf][nf][rr]);
        }
  }
}

// ---------------- MFMA mix. mode: 0 = mb hi/lo (+bias); 1 = m f32 (+bias); 3 = m += (no bias)
template<int NCH>
__global__ __launch_bounds__(256) void k_mix(const u16* c0,const u16* c1,const u16* c2,const u16* c3,
                                             const u16* c4,const u16* c5,const u16* c6,
                                             int wcol0,
                                             const u16* __restrict__ WH, const u16* __restrict__ WL,
                                             const float* __restrict__ bm,
                                             float* __restrict__ m, u16* __restrict__ mbh, u16* __restrict__ mbl,
                                             int mode){
  __shared__ __align__(16) u16 lds[2][8192];
  int tid = threadIdx.x, bid = blockIdx.x;
  int b = bid >> 8, t = bid & 255;
  size_t cbase = ((size_t)(b*256 + t)) * 8192;
  const u16* chp[7] = {c0,c1,c2,c3,c4,c5,c6};
  int lane = tid & 63, wave = tid >> 6;

  short8 wh[NCH][2], wl[NCH][2];
  #pragma unroll
  for(int k=0;k<NCH;k++)
    #pragma unroll
    for(int ot=0;ot<2;ot++){
      int wi = (ot*16 + (lane&15))*224 + (wcol0 + k)*32 + (lane>>4)*8;
      wh[k][ot] = *(const short8*)(WH + wi);
      wl[k][ot] = *(const short8*)(WL + wi);
    }

  {
    const u16* g = chp[0] + cbase;
    #pragma unroll
    for(int i=0;i<4;i++){
      int off = i*4096 + tid*16;
      int c = off>>9, byte = off&511;
      short8 v = *(const short8*)(g + (off>>1));
      *(short8*)((char*)&lds[0][0] + c*512 + (byte ^ ((c&24)<<2))) = v;
    }
  }
  __syncthreads();

  f32x4 acc[2][4];
  #pragma unroll
  for(int a=0;a<2;a++)
    #pragma unroll
    for(int q=0;q<4;q++) acc[a][q] = {0.f,0.f,0.f,0.f};

  int buf = 0;
  #pragma unroll
  for(int k=0;k<NCH;k++){
    if(k+1 < NCH){
      const u16* g = chp[k+1] + cbase;
      #pragma unroll
      for(int i=0;i<4;i++){
        int off = i*4096 + tid*16;
        int c = off>>9, byte = off&511;
        short8 v = *(const short8*)(g + (off>>1));
        *(short8*)((char*)&lds[buf^1][0] + c*512 + (byte ^ ((c&24)<<2))) = v;
      }
    }
    #pragma unroll
    for(int nf=0; nf<4; nf++){
      int n = (wave<<6) + (nf<<4) + (lane & 15);
      short8 v;
      #pragma unroll
      for(int j=0;j<8;j++){
        int c = ((lane>>4)<<3) + j;
        v[j] = *(const short*)((const char*)&lds[buf][0] + c*512 + ((n*2) ^ ((c&24)<<2)));
      }
      #pragma unroll
      for(int ot=0;ot<2;ot++){
        acc[ot][nf] = __builtin_amdgcn_mfma_f32_16x16x32_bf16(wh[k][ot], v, acc[ot][nf], 0,0,0);
        acc[ot][nf] = __builtin_amdgcn_mfma_f32_16x16x32_bf16(wl[k][ot], v, acc[ot][nf], 0,0,0);
      }
    }
    __syncthreads();
    buf ^= 1;
  }

  #pragma unroll
  for(int ot=0;ot<2;ot++)
    #pragma unroll
    for(int nf=0;nf<4;nf++)
      #pragma unroll
      for(int rr=0;rr<4;rr++){
        int o = ot*16 + (lane>>4)*4 + rr;
        int n = (wave<<6) + (nf<<4) + (lane&15);
        size_t a = cbase + (size_t)o*256 + n;
        float val = acc[ot][nf][rr];
        if(!(mode & 2)) val += bm[o];
        if(mode & 1){
          if(mode & 2) m[a] += val; else m[a] = val;
        } else {
          u16 hh = f2bf(val);
          mbh[a] = hh;
          mbl[a] = f2bf(val - bf2f(hh));
        }
      }
}

// ---------------- m f32 -> mb hi/lo bf16 (tier C)
__global__ __launch_bounds__(256) void k_h2b(const float* __restrict__ m, u16* __restrict__ mbh, u16* __restrict__ mbl){
  size_t i = ((size_t)blockIdx.x*256 + threadIdx.x)*4;
  f32x4 v = *(const f32x4*)(m + i);
  short4v h, l;
  #pragma unroll
  for(int j=0;j<4;j++){
    u16 hh = f2bf(v[j]);
    h[j] = (short)hh;
    l[j] = (short)f2bf(v[j] - bf2f(hh));
  }
  *(short4v*)(mbh + i) = h;
  *(short4v*)(mbl + i) = l;
}

// ---------------- m [b][t][o][n] f32 -> dst [b][o][n][t] f32
__global__ __launch_bounds__(256) void k_tip(const float* __restrict__ m, float* __restrict__ dst){
  int tile = blockIdx.x & 15; int slice = blockIdx.x >> 4;
  int b = slice >> 5, o = slice & 31;
  int tn0 = (tile & 3) * 64, tt0 = (tile >> 2) * 64;
  __shared__ float l[64][65];
  int cc = threadIdx.x & 63, r0 = threadIdx.x >> 6;
  #pragma unroll
  for(int k=0;k<16;k++){ int r = r0 + 4*k;
    l[r][cc] = m[(((size_t)b*256 + (tt0+r))*32 + o)*256 + tn0 + cc];
  }
  __syncthreads();
  #pragma unroll
  for(int k=0;k<16;k++){ int r = r0 + 4*k;
    dst[(((size_t)b*32 + o)*256 + (tn0+r))*256 + tt0 + cc] = l[cc][r];
  }
}

extern "C" void kernel_launch(void* const* d_in, const int* in_sizes, int n_in,
                              void* d_out, int out_size, void* d_ws, size_t ws_size,
                              hipStream_t stream){
  (void)in_sizes; (void)n_in; (void)out_size;
  const float* x    = (const float*)d_in[0];
  const float* nv1  = (const float*)d_in[1];
  const float* nv2  = (const float*)d_in[2];
  const float* sup0 = (const float*)d_in[3];
  const float* sup1 = (const float*)d_in[4];
  const float* wf1 = (const float*)d_in[5];  const float* bf1v = (const float*)d_in[6];
  const float* wg1 = (const float*)d_in[7];  const float* bg1v = (const float*)d_in[8];
  const float* wf2 = (const float*)d_in[9];  const float* bf2v = (const float*)d_in[10];
  const float* wg2 = (const float*)d_in[11]; const float* bg2v = (const float*)d_in[12];
  const float* wm1 = (const float*)d_in[13]; const float* bm1 = (const float*)d_in[14];
  const float* wm2 = (const float*)d_in[15]; const float* bm2 = (const float*)d_in[16];
  float* out = (float*)d_out;
  char* ws = (char*)d_ws;
  const size_t MB = (size_t)1 << 20;

  u16*  badj  = (u16*)ws;
  u16*  badj2 = (u16*)(ws + 393216);
  float* adp  = (float*)(ws + 786432);
  u16*  whi   = (u16*)(ws + 1048576);
  u16*  wlo   = (u16*)(ws + 1077248);
  u16*  wcp   = (u16*)(ws + 1105920);

  int tier = (ws_size >= 178*MB) ? 0 : ((ws_size >= 146*MB) ? 1 : 2);
  u16* h = (u16*)(ws + 2*MB);
  u16 *xT, *mbh, *mbl, *Y[6] = {0,0,0,0,0,0};
  float *m, *tmp = nullptr;
  if(tier <= 1){
    for(int k=0;k<6;k++) Y[k] = (u16*)(ws + (18 + 16*(size_t)k)*MB);
    mbh = (u16*)(ws + 114*MB); xT = mbh;
    mbl = (u16*)(ws + 130*MB);
    if(tier==0){ m = (float*)(ws + 146*MB); }
    else { m = out; tmp = (float*)(ws + 18*MB); }
  } else {
    Y[0] = (u16*)(ws + 18*MB);
    Y[1] = (u16*)(ws + 34*MB);
    xT = Y[0]; mbh = Y[0]; mbl = Y[1];
    m = out; tmp = (float*)(ws + 18*MB);
  }

  k_adp<<<256,256,0,stream>>>(nv1, nv2, adp);
  k_badj<<<768,256,0,stream>>>(sup0, sup1, adp, badj);
  k_wprep<<<88,256,0,stream>>>(wm1, wm2, wf1, wg1, wf2, wg2, whi, wlo, wcp);
  k_asq<<<12,256,0,stream>>>(badj, sup0, sup1, adp, badj2);
  k_tin<<<2048,256,0,stream>>>(x, xT);

  for(int blk=0; blk<2; blk++){
    if(blk==0) k_cv<0><<<1024,256,0,stream>>>(xT, (const u16*)0, wcp, 0, 1, bf1v, bg1v, h);
    else       k_cv<1><<<1024,256,0,stream>>>(mbh, mbl,          wcp, 1, 2, bf2v, bg2v, h);
    const u16* WH = whi + blk*7168;
    const u16* WL = wlo + blk*7168;
    const float* bm = blk ? bm2 : bm1;
    if(tier <= 1){
      k_hop6<6><<<512,256,0,stream>>>(h, Y[0],Y[1],Y[2],Y[3],Y[4],Y[5], badj, badj2, 0);
      if(blk==0) k_mix<7><<<1024,256,0,stream>>>(h,Y[0],Y[1],Y[2],Y[3],Y[4],Y[5], 0, WH,WL,bm, (float*)0, mbh, mbl, 0);
      else       k_mix<7><<<1024,256,0,stream>>>(h,Y[0],Y[1],Y[2],Y[3],Y[4],Y[5], 0, WH,WL,bm, m, (u16*)0, (u16*)0, 1);
    } else {
      k_mix<1><<<1024,256,0,stream>>>(h,0,0,0,0,0,0, 0, WH,WL,bm, m, (u16*)0, (u16*)0, 1);
      for(int s=0;s<3;s++){
        k_hop6<2><<<512,256,0,stream>>>(h, Y[0],Y[1],0,0,0,0, badj, badj2, 2*s);
        k_mix<2><<<1024,256,0,stream>>>(Y[0],Y[1],0,0,0,0,0, 1+2*s, WH,WL,bm, m, (u16*)0, (u16*)0, 3);
      }
      if(blk==0) k_h2b<<<8192,256,0,stream>>>(m, mbh, mbl);
    }
  }
  if(tier==0){
    k_tip<<<2048,256,0,stream>>>(m, out);
  } else {
    k_tip<<<2048,256,0,stream>>>(m, tmp);
    hipMemcpyAsync(out, tmp, (size_t)32*MB, hipMemcpyDeviceToDevice, stream);
  }
}